// Round 1
// 511.861 us; speedup vs baseline: 1.0121x; 1.0121x over previous
//
#include <hip/hip_runtime.h>
#include <hip/hip_bf16.h>
#include <cfloat>
#include <math.h>

// Problem: B=4,T=32,N=96,K=30, NUM_HIDDEN=128, NUM_IN=256, H=4, d=32
constexpr int SITES = 12288;
constexpr int KNB   = 30;
constexpr int CIN   = 256;
#define RSQRT_D 0.17677669529663689f

typedef short bf16x8 __attribute__((ext_vector_type(8)));   // 8 bf16 in 4 VGPRs
typedef float f32x4  __attribute__((ext_vector_type(4)));

__device__ inline unsigned short f2bs(float x) {
    __hip_bfloat16 b = __float2bfloat16(x);            // RTN-even
    return *(unsigned short*)&b;
}
__device__ inline float bs2f(unsigned short u) {
    unsigned int v = (unsigned int)u << 16;
    float f;
    __builtin_memcpy(&f, &v, 4);
    return f;
}
__device__ inline unsigned int pack2(float a, float b) {
    return (unsigned int)f2bs(a) | ((unsigned int)f2bs(b) << 16);
}

// ---------------------------------------------------------------------------
// Weight precompute (bf16, transposed for B^T GEMM):
//   Mt[(h*256+c)*128 + i] = sum_d Wq[i][h*32+d] * Wk[c][h*32+d]   (1024 x 128)
//   W3t[j*1024 + h*256+c] = sum_d Wv[c][h*32+d] * Wo[h*32+d][j]   (128 x 1024)
// Mt half: lanes vary i -> Wq gather is float4-vectorized, Wk broadcast.
// W3t half: REMAPPED so lanes vary j -> Wo reads coalesced, Wv broadcast,
//           single scatter store (replaces 32 gather loads/thread).
// ---------------------------------------------------------------------------
__global__ __launch_bounds__(256) void precompute_w(
    const float* __restrict__ Wq, const float* __restrict__ Wk,
    const float* __restrict__ Wv, const float* __restrict__ Wo,
    unsigned short* __restrict__ Mt, unsigned short* __restrict__ W3t) {
    int gid = blockIdx.x * 256 + threadIdx.x;
    if (gid < 131072) {
        int p = gid >> 7;          // h*256+c
        int i = gid & 127;
        int h = p >> 8;
        int c = p & 255;
        const float4* wq = (const float4*)(Wq + (size_t)i * 128 + h * 32);
        const float4* wk = (const float4*)(Wk + (size_t)c * 128 + h * 32);
        float s = 0.f;
        #pragma unroll
        for (int d = 0; d < 8; ++d) {
            float4 a = wq[d], b = wk[d];
            s += a.x * b.x; s += a.y * b.y; s += a.z * b.z; s += a.w * b.w;
        }
        Mt[gid] = f2bs(s);
    } else {
        int o = gid - 131072;
        int p = o >> 7;            // h*256+c  (wave-uniform)
        int j = o & 127;           // lanes vary j -> coalesced Wo
        int h = p >> 8;
        int c = p & 255;
        const float* wv = Wv + (size_t)c * 128 + h * 32;
        const float* wo = Wo + (size_t)(h * 32) * 128 + j;
        float s = 0.f;
        #pragma unroll
        for (int d = 0; d < 32; ++d)
            s += wv[d] * wo[(size_t)d * 128];
        W3t[(size_t)j * 1024 + p] = f2bs(s);
    }
}

// ---------------------------------------------------------------------------
// bf16 MFMA GEMM, B^T input:  C(MxN) = A(MxK) @ Bt(NxK)^T
// block = 256 thr (4 waves), BM=64 (16 rows/wave), BN=128, BK=32
// A_F32: A is fp32 and converted to bf16 during staging (absorbs convert_hv).
// ---------------------------------------------------------------------------
template <bool OUT_BF16, bool A_F32>
__global__ __launch_bounds__(256) void gemm_bt_bf16(
    const void* __restrict__ Aptr, const unsigned short* __restrict__ Bt,
    void* __restrict__ C, int M, int N, int K) {
    constexpr int BM = 64, BN = 128, BK = 32, PAD = 8;
    constexpr int NT = BN / 16;                       // 8 n-tiles per wave
    __shared__ unsigned short As[BM][BK + PAD];       // 5 KB
    __shared__ unsigned short Bs[BN][BK + PAD];       // 10 KB
    const int tid  = threadIdx.x;
    const int wave = tid >> 6;
    const int lane = tid & 63;
    const int quad = lane >> 4;
    const int l16  = lane & 15;
    const int bm0 = blockIdx.x * BM;
    const int bn0 = blockIdx.y * BN;

    f32x4 acc[NT];
    #pragma unroll
    for (int j = 0; j < NT; ++j) acc[j] = (f32x4){0.f, 0.f, 0.f, 0.f};

    for (int kk = 0; kk < K; kk += BK) {
        {   // stage A: 64*32/8 = 256 chunks (1/thread)
            int row = tid >> 2, off = (tid & 3) * 8;
            if (A_F32) {
                const float* Af = (const float*)Aptr;
                const float4* src = (const float4*)&Af[(size_t)(bm0 + row) * K + kk + off];
                float4 a0 = src[0], a1 = src[1];
                uint4 p;
                p.x = pack2(a0.x, a0.y); p.y = pack2(a0.z, a0.w);
                p.z = pack2(a1.x, a1.y); p.w = pack2(a1.z, a1.w);
                *(uint4*)&As[row][off] = p;
            } else {
                const unsigned short* Ab = (const unsigned short*)Aptr;
                *(uint4*)&As[row][off] =
                    *(const uint4*)&Ab[(size_t)(bm0 + row) * K + kk + off];
            }
        }
        #pragma unroll
        for (int i = 0; i < 2; ++i) {   // stage Bt: 128*32/8 = 512 chunks
            int c2 = tid * 2 + i;
            int brow = c2 >> 2, boff = (c2 & 3) * 8;
            *(uint4*)&Bs[brow][boff] =
                *(const uint4*)&Bt[(size_t)(bn0 + brow) * K + kk + boff];
        }
        __syncthreads();
        bf16x8 af = *(const bf16x8*)&As[wave * 16 + l16][quad * 8];
        #pragma unroll
        for (int j = 0; j < NT; ++j) {
            bf16x8 bf = *(const bf16x8*)&Bs[j * 16 + l16][quad * 8];
            acc[j] = __builtin_amdgcn_mfma_f32_16x16x32_bf16(af, bf, acc[j], 0, 0, 0);
        }
        __syncthreads();
    }
    // C/D layout: col = lane&15, row = quad*4 + reg  (m89-verified)
    int row0 = bm0 + wave * 16 + quad * 4;
    #pragma unroll
    for (int j = 0; j < NT; ++j) {
        int col = bn0 + j * 16 + l16;
        #pragma unroll
        for (int r = 0; r < 4; ++r) {
            if (OUT_BF16)
                ((unsigned short*)C)[(size_t)(row0 + r) * N + col] = f2bs(acc[j][r]);
            else
                ((float*)C)[(size_t)(row0 + r) * N + col] = acc[j][r];
        }
    }
}

// ---------------------------------------------------------------------------
// Fused masked neighbor attention. One block (4 waves) per site.
//  Phase 0 : wave0 builds active-row list; waves1-2 stage q~ (2KB bf16) to
//            LDS as f32 ONCE (was: every thread re-loading/unpacking 16x).
//  Phase 1 : each lane reads its q fragment (8 ch x 4 heads = 32 VGPR) from
//            LDS; half-wave per active row: 2 coalesced float4 loads (32B),
//            bf16 LDS stage, 4-head dot, 5-stage shuffle reduce.
//  Phase 2 : softmax per head (wave h).
//  Phase 3 : evbar accum from LDS (thread = column), bf16 output.
// ---------------------------------------------------------------------------
__global__ __launch_bounds__(256) void attn_kernel(
    const float* __restrict__ hEV, const int* __restrict__ mask,
    const unsigned short* __restrict__ qt, unsigned short* __restrict__ evb) {
    __shared__ unsigned short evS[KNB * CIN];   // 15 KB (bf16)
    __shared__ float qS[1024];                  // 4 KB (q~ as f32)
    __shared__ float logitsL[4 * 32];
    __shared__ float attendL[4 * 32];
    __shared__ int   activeS[32];
    __shared__ int   naS;

    const int s = blockIdx.x;
    const int tid = threadIdx.x;
    const int lane = tid & 63;
    const int wv = tid >> 6;
    const int hw = lane >> 5;        // half-wave id
    const int sl = lane & 31;        // lane within half

    // --- phase 0: active list (wave 0) + q~ staging (waves 1-2) ---
    if (tid < 64) {
        int mk = (tid < KNB) ? mask[(size_t)s * KNB + tid] : 0;
        unsigned long long bal = __ballot(mk > 0);
        if (tid == 0) naS = __popcll(bal);
        if (mk > 0) activeS[__popcll(bal & ((1ull << tid) - 1))] = tid;
    } else if (tid < 192) {
        int t2 = tid - 64;           // 0..127, one uint4 (8 bf16) each
        uint4 u = ((const uint4*)(qt + (size_t)s * 1024))[t2];
        float f[8];
        f[0] = bs2f(u.x & 0xffff); f[1] = bs2f(u.x >> 16);
        f[2] = bs2f(u.y & 0xffff); f[3] = bs2f(u.y >> 16);
        f[4] = bs2f(u.z & 0xffff); f[5] = bs2f(u.z >> 16);
        f[6] = bs2f(u.w & 0xffff); f[7] = bs2f(u.w >> 16);
        *(float4*)&qS[t2 * 8]     = *(float4*)&f[0];
        *(float4*)&qS[t2 * 8 + 4] = *(float4*)&f[4];
    }
    __syncthreads();

    // --- per-lane q fragment: channels sl*8 .. sl*8+7, all 4 heads ---
    float qf[4][8];
    #pragma unroll
    for (int h = 0; h < 4; ++h) {
        *(float4*)&qf[h][0] = *(const float4*)&qS[h * 256 + sl * 8];
        *(float4*)&qf[h][4] = *(const float4*)&qS[h * 256 + sl * 8 + 4];
    }
    const int na = naS;

    // --- stream active rows: half-wave per row (8 in flight per pass) ---
    for (int r = wv * 2 + hw; r < na; r += 8) {
        int k = activeS[r];
        const float* row = hEV + (size_t)s * (KNB * CIN) + (size_t)k * CIN + sl * 8;
        float4 v0 = *(const float4*)row;
        float4 v1 = *(const float4*)(row + 4);

        uint4 p;
        p.x = pack2(v0.x, v0.y); p.y = pack2(v0.z, v0.w);
        p.z = pack2(v1.x, v1.y); p.w = pack2(v1.z, v1.w);
        *(uint4*)&evS[r * CIN + sl * 8] = p;

        float l[4];
        #pragma unroll
        for (int h = 0; h < 4; ++h) {
            l[h] = v0.x * qf[h][0] + v0.y * qf[h][1] + v0.z * qf[h][2] + v0.w * qf[h][3]
                 + v1.x * qf[h][4] + v1.y * qf[h][5] + v1.z * qf[h][6] + v1.w * qf[h][7];
        }
        #pragma unroll
        for (int m = 1; m < 32; m <<= 1) {
            #pragma unroll
            for (int h = 0; h < 4; ++h) l[h] += __shfl_xor(l[h], m, 64);
        }
        if (sl == 0) {
            #pragma unroll
            for (int h = 0; h < 4; ++h) logitsL[h * 32 + r] = l[h] * RSQRT_D;
        }
    }
    __syncthreads();

    // --- softmax over active slots: wave h ---
    {
        float lg = (lane < na) ? logitsL[wv * 32 + lane] : -FLT_MAX;
        float mx = lg;
        #pragma unroll
        for (int m = 1; m < 64; m <<= 1) mx = fmaxf(mx, __shfl_xor(mx, m, 64));
        float e = (lane < na) ? __expf(lg - mx) : 0.f;
        float sm = e;
        #pragma unroll
        for (int m = 1; m < 64; m <<= 1) sm += __shfl_xor(sm, m, 64);
        if (lane < na) attendL[wv * 32 + lane] = e / sm;
    }
    __syncthreads();

    // --- evbar: thread t owns column c = t ---
    float a0 = 0.f, a1 = 0.f, a2 = 0.f, a3 = 0.f;
    for (int r = 0; r < na; ++r) {
        float evv = bs2f(evS[r * CIN + tid]);
        a0 = fmaf(attendL[r], evv, a0);
        a1 = fmaf(attendL[32 + r], evv, a1);
        a2 = fmaf(attendL[64 + r], evv, a2);
        a3 = fmaf(attendL[96 + r], evv, a3);
    }
    size_t ob = (size_t)s * 1024 + tid;
    evb[ob]       = f2bs(a0);
    evb[ob + 256] = f2bs(a1);
    evb[ob + 512] = f2bs(a2);
    evb[ob + 768] = f2bs(a3);
}

// ---------------------------------------------------------------------------
extern "C" void kernel_launch(void* const* d_in, const int* in_sizes, int n_in,
                              void* d_out, int out_size, void* d_ws, size_t ws_size,
                              hipStream_t stream) {
    const float* hV   = (const float*)d_in[0];
    const float* hEV  = (const float*)d_in[1];
    const int*   mask = (const int*)d_in[2];
    const float* Wq   = (const float*)d_in[3];
    const float* Wk   = (const float*)d_in[4];
    const float* Wv   = (const float*)d_in[5];
    const float* Wo   = (const float*)d_in[6];
    float* out = (float*)d_out;

    unsigned short* ws = (unsigned short*)d_ws;   // element = 2 B
    unsigned short* Mt   = ws;                            // 1024*128
    unsigned short* W3t  = ws + 131072;                   // 128*1024
    unsigned short* qt   = ws + 262144;                   // 12288*1024
    unsigned short* evb  = qt + (size_t)SITES * 1024;     // 12288*1024
    size_t need = ((size_t)262144 + 2 * (size_t)SITES * 1024) * 2;
    if (ws_size < need) return;

    precompute_w<<<dim3(1024), dim3(256), 0, stream>>>(Wq, Wk, Wv, Wo, Mt, W3t);

    // qt (12288x1024, bf16) = bf16(hV) (12288x128) @ Mt^T   (conversion fused)
    gemm_bt_bf16<true, true><<<dim3(SITES / 64, 1024 / 128), dim3(256), 0, stream>>>(
        hV, Mt, qt, SITES, 1024, 128);

    // fused masked attention -> evb (12288x1024, bf16)
    attn_kernel<<<dim3(SITES), dim3(256), 0, stream>>>(hEV, mask, qt, evb);

    // out (12288x128, fp32) = evb @ W3t^T
    gemm_bt_bf16<false, false><<<dim3(SITES / 64, 1), dim3(256), 0, stream>>>(
        evb, W3t, out, SITES, 128, 1024);
}